// Round 6
// baseline (288.779 us; speedup 1.0000x reference)
//
#include <hip/hip_runtime.h>
#include <stdint.h>

#define NB 8
#define NC 8
#define NN 1024
#define ND 256
#define KK 2048      // NC * ND
#define BM 128
#define BN 64
#define BKK 64
#define NT (KK / BKK)

typedef float f32x4 __attribute__((ext_vector_type(4)));
typedef short bf16x8 __attribute__((ext_vector_type(8)));

__device__ __forceinline__ unsigned short f2bf(float x) {
  union { float f; uint32_t u; } a; a.f = x;
  uint32_t u = a.u;
  return (unsigned short)((u + 0x7FFFu + ((u >> 16) & 1u)) >> 16);  // RTNE
}

// Pass 1: per (b,c,n) row of 256 f32: sq=sum g^2, rnorm=rsqrt(sum g^4);
// ghat[b][n][c*256+d] = bf16(g*rnorm); uFlat[rowid]=sq*rnorm, vFlat[rowid]=rnorm.
__global__ __launch_bounds__(256) void prep_kernel(
    const float* __restrict__ g, unsigned short* __restrict__ ghat,
    float* __restrict__ uFlat, float* __restrict__ vFlat) {
  int tid = threadIdx.x;
  int wave = tid >> 6, lane = tid & 63;
  int sub = lane & 15, grp = lane >> 4;
  int rowid = (blockIdx.x * 4 + wave) * 4 + grp;      // 16 rows per block
  const float* row = g + (size_t)rowid * ND;
  f32x4 v[4];
  float s2 = 0.f, s4 = 0.f;
#pragma unroll
  for (int q = 0; q < 4; ++q) {
    v[q] = *(const f32x4*)(row + q * 64 + sub * 4);
#pragma unroll
    for (int e = 0; e < 4; ++e) { float x2 = v[q][e] * v[q][e]; s2 += x2; s4 += x2 * x2; }
  }
#pragma unroll
  for (int off = 8; off; off >>= 1) {                 // reduce within 16-lane group
    s2 += __shfl_xor(s2, off);
    s4 += __shfl_xor(s4, off);
  }
  float rn = rsqrtf(s4);
  int n = rowid & (NN - 1);
  int bc = rowid >> 10;
  int c = bc & (NC - 1);
  int b = bc >> 3;
  unsigned short* dst = ghat + ((size_t)(b * NN + n)) * KK + (size_t)c * ND + sub * 4;
#pragma unroll
  for (int q = 0; q < 4; ++q) {
    ushort4 o;
    o.x = f2bf(v[q][0] * rn); o.y = f2bf(v[q][1] * rn);
    o.z = f2bf(v[q][2] * rn); o.w = f2bf(v[q][3] * rn);
    *(ushort4*)(dst + q * 64) = o;
  }
  if (sub == 0) { uFlat[rowid] = s2 * rn; vFlat[rowid] = rn; }
}

// Pass 2: per b, out = 0.125*(u_n.v_m + v_n.u_m) - 0.25 * <ghat_n, ghat_m>
// NO LDS in the main loop: MFMA fragments are loaded global->VGPR directly.
// Per XCD the ghat panel is 4MB (L2-resident; XCD swizzle pins it), so LDS
// staging was pure overhead (DMA + barriers + wide-op LDS phases). With no
// barriers the compiler software-pipelines loads across K-steps and ~16
// resident waves/CU hide L2 latency.
__global__ __launch_bounds__(256) void gram_gemm_kernel(
    const unsigned short* __restrict__ ghat,
    const float* __restrict__ uFlat, const float* __restrict__ vFlat,
    float* __restrict__ out) {
  __shared__ struct { float R[128][16]; float Cc[64][16]; } sm;   // epilogue only, 12 KiB

  // XCD swizzle: 1024 blocks, 8 XCDs -> 128 consecutive logical tiles
  // (= one full batch b, one 4MiB ghat panel) per XCD L2.
  int bid = blockIdx.x;
  int logical = (bid & 7) * 128 + (bid >> 3);
  int b = logical >> 7;
  int t7 = logical & 127;
  int row0 = (t7 >> 4) * BM;   // 8 row tiles
  int col0 = (t7 & 15) * BN;   // 16 col tiles
  int tid = threadIdx.x;
  int lane = tid & 63;
  int wave = tid >> 6;
  int wr = (wave >> 1) * 64;   // 2x2 wave grid: 64x32 out per wave
  int wc = (wave & 1) * 32;

  int rsel = lane & 15;        // fragment row selector
  int khalf = lane >> 4;       // k-chunk selector (0..3)

  // Per-lane fragment base pointers (loop-invariant).
  const unsigned short* baseA =
      ghat + (size_t)(b * NN + row0 + wr + rsel) * KK + khalf * 8;
  const unsigned short* baseB =
      ghat + (size_t)(b * NN + col0 + wc + rsel) * KK + khalf * 8;

  f32x4 acc[4][2];
#pragma unroll
  for (int i = 0; i < 4; ++i)
#pragma unroll
    for (int j = 0; j < 2; ++j)
      acc[i][j] = f32x4{0.f, 0.f, 0.f, 0.f};

#pragma unroll 2
  for (int t = 0; t < NT; ++t) {
    int k0 = t * BKK;
    bf16x8 af[4][2], bfb[2][2];
#pragma unroll
    for (int kk = 0; kk < 2; ++kk) {
#pragma unroll
      for (int i = 0; i < 4; ++i)
        af[i][kk] = *(const bf16x8*)(baseA + (size_t)i * 16 * KK + k0 + kk * 32);
#pragma unroll
      for (int j = 0; j < 2; ++j)
        bfb[j][kk] = *(const bf16x8*)(baseB + (size_t)j * 16 * KK + k0 + kk * 32);
    }
#pragma unroll
    for (int kk = 0; kk < 2; ++kk)
#pragma unroll
      for (int i = 0; i < 4; ++i)
#pragma unroll
        for (int j = 0; j < 2; ++j)
          acc[i][j] = __builtin_amdgcn_mfma_f32_16x16x32_bf16(af[i][kk], bfb[j][kk], acc[i][j], 0, 0, 0);
  }

  // Gather u/v (flat layout) into LDS: R[rl][0..7]=u_row, [8..15]=v_row;
  // Cc[cl][0..7]=u_col, [8..15]=v_col.
  {
    int rl = tid >> 1;                 // 0..127
    int half = tid & 1;                // 0 = u, 1 = v
    const float* src = half ? vFlat : uFlat;
#pragma unroll
    for (int c = 0; c < 8; ++c)
      sm.R[rl][half * 8 + c] = src[(size_t)(b * NC + c) * NN + row0 + rl];
    if (rl < 64) {
#pragma unroll
      for (int c = 0; c < 8; ++c)
        sm.Cc[rl][half * 8 + c] = src[(size_t)(b * NC + c) * NN + col0 + rl];
    }
  }
  __syncthreads();

  int lr = (lane >> 4) * 4;
  int lc = lane & 15;
#pragma unroll
  for (int j = 0; j < 2; ++j) {
    int cl = wc + j * 16 + lc;
    f32x4 uc0 = *(const f32x4*)&sm.Cc[cl][0];
    f32x4 uc1 = *(const f32x4*)&sm.Cc[cl][4];
    f32x4 vc0 = *(const f32x4*)&sm.Cc[cl][8];
    f32x4 vc1 = *(const f32x4*)&sm.Cc[cl][12];
#pragma unroll
    for (int i = 0; i < 4; ++i) {
#pragma unroll
      for (int q = 0; q < 4; ++q) {
        int rl = wr + i * 16 + lr + q;
        f32x4 r0 = *(const f32x4*)&sm.R[rl][0];
        f32x4 r1 = *(const f32x4*)&sm.R[rl][4];
        f32x4 r2 = *(const f32x4*)&sm.R[rl][8];
        f32x4 r3 = *(const f32x4*)&sm.R[rl][12];
        float fr = r0[0]*vc0[0]+r0[1]*vc0[1]+r0[2]*vc0[2]+r0[3]*vc0[3]
                 + r1[0]*vc1[0]+r1[1]*vc1[1]+r1[2]*vc1[2]+r1[3]*vc1[3]
                 + r2[0]*uc0[0]+r2[1]*uc0[1]+r2[2]*uc0[2]+r2[3]*uc0[3]
                 + r3[0]*uc1[0]+r3[1]*uc1[1]+r3[2]*uc1[2]+r3[3]*uc1[3];
        float val = 0.125f * fr - 0.25f * acc[i][j][q];
        out[((size_t)(b * NN + row0 + rl)) * NN + (size_t)(col0 + cl)] = val;
      }
    }
  }
}

extern "C" void kernel_launch(void* const* d_in, const int* in_sizes, int n_in,
                              void* d_out, int out_size, void* d_ws, size_t ws_size,
                              hipStream_t stream) {
  const float* g = (const float*)d_in[0];
  // d_in[1] = patchPerRow (unused by the reference computation)
  unsigned short* ghat = (unsigned short*)d_ws;                          // 32 MiB bf16
  float* uFlat = (float*)((char*)d_ws + (size_t)NB * NN * KK * 2);       // 256 KiB
  float* vFlat = uFlat + (size_t)NB * NC * NN;                           // 256 KiB
  float* outp = (float*)d_out;

  prep_kernel<<<NB * NC * NN / 16, 256, 0, stream>>>(g, ghat, uFlat, vFlat);
  gram_gemm_kernel<<<1024, 256, 0, stream>>>(ghat, uFlat, vFlat, outp);
}

// Round 7
// 200.016 us; speedup vs baseline: 1.4438x; 1.4438x over previous
//
#include <hip/hip_runtime.h>
#include <stdint.h>

#define NB 8
#define NC 8
#define NN 1024
#define ND 256
#define KK 2048      // NC * ND
#define BM 256
#define BN 128
#define BKK 64
#define NT (KK / BKK)

typedef float f32x4 __attribute__((ext_vector_type(4)));
typedef short bf16x8 __attribute__((ext_vector_type(8)));

__device__ __forceinline__ unsigned short f2bf(float x) {
  union { float f; uint32_t u; } a; a.f = x;
  uint32_t u = a.u;
  return (unsigned short)((u + 0x7FFFu + ((u >> 16) & 1u)) >> 16);  // RTNE
}

__device__ __forceinline__ void gload16(const void* g, void* l) {
  __builtin_amdgcn_global_load_lds(
      (__attribute__((address_space(1))) uint32_t*)g,
      (__attribute__((address_space(3))) uint32_t*)l, 16, 0, 0);
}

// Pass 1: per (b,c,n) row of 256 f32: sq=sum g^2, rnorm=rsqrt(sum g^4);
// ghat[b][n][c*256+d] = bf16(g*rnorm); uFlat[rowid]=sq*rnorm, vFlat[rowid]=rnorm.
__global__ __launch_bounds__(256) void prep_kernel(
    const float* __restrict__ g, unsigned short* __restrict__ ghat,
    float* __restrict__ uFlat, float* __restrict__ vFlat) {
  int tid = threadIdx.x;
  int wave = tid >> 6, lane = tid & 63;
  int sub = lane & 15, grp = lane >> 4;
  int rowid = (blockIdx.x * 4 + wave) * 4 + grp;      // 16 rows per block
  const float* row = g + (size_t)rowid * ND;
  f32x4 v[4];
  float s2 = 0.f, s4 = 0.f;
#pragma unroll
  for (int q = 0; q < 4; ++q) {
    v[q] = *(const f32x4*)(row + q * 64 + sub * 4);
#pragma unroll
    for (int e = 0; e < 4; ++e) { float x2 = v[q][e] * v[q][e]; s2 += x2; s4 += x2 * x2; }
  }
#pragma unroll
  for (int off = 8; off; off >>= 1) {                 // reduce within 16-lane group
    s2 += __shfl_xor(s2, off);
    s4 += __shfl_xor(s4, off);
  }
  float rn = rsqrtf(s4);
  int n = rowid & (NN - 1);
  int bc = rowid >> 10;
  int c = bc & (NC - 1);
  int b = bc >> 3;
  unsigned short* dst = ghat + ((size_t)(b * NN + n)) * KK + (size_t)c * ND + sub * 4;
#pragma unroll
  for (int q = 0; q < 4; ++q) {
    ushort4 o;
    o.x = f2bf(v[q][0] * rn); o.y = f2bf(v[q][1] * rn);
    o.z = f2bf(v[q][2] * rn); o.w = f2bf(v[q][3] * rn);
    *(ushort4*)(dst + q * 64) = o;
  }
  if (sub == 0) { uFlat[rowid] = s2 * rn; vFlat[rowid] = rn; }
}

// Pass 2: per b, out = 0.125*(u_n.v_m + v_n.u_m) - 0.25 * <ghat_n, ghat_m>
// 256x128 tile, 8 waves (4x2), 64x64 out/wave (4x4 frags): 32 MFMA per 16
// ds_read_b128 per wave per K-step (2x the FLOP:LDS ratio of the 128x64
// version) and half the barriers/staged-bytes per FLOP. Counted-vmcnt
// double-buffer with raw s_barrier (no vmcnt(0) drain in the loop).
// Grid = 256 blocks = 1/CU; 96 KiB LDS.
__global__ __launch_bounds__(512, 2) void gram_gemm_kernel(
    const unsigned short* __restrict__ ghat,
    const float* __restrict__ uFlat, const float* __restrict__ vFlat,
    float* __restrict__ out) {
  __shared__ union {
    struct { unsigned short A[2][BM * BKK]; unsigned short Bt[2][BN * BKK]; } s;  // 96 KiB
    struct { float R[256][16]; float Cc[128][16]; } e;                            // 24 KiB
  } sm;

  // XCD swizzle: 256 blocks, 8 XCDs -> 32 consecutive logical tiles
  // (= one full batch b, one 4MiB ghat panel) per XCD L2.
  int bid = blockIdx.x;
  int logical = (bid & 7) * 32 + (bid >> 3);
  int b = logical >> 5;
  int t5 = logical & 31;
  int row0 = (t5 >> 3) * BM;   // 4 row tiles
  int col0 = (t5 & 7) * BN;    // 8 col tiles
  int tid = threadIdx.x;
  int lane = tid & 63;
  int wave = tid >> 6;
  int wr = (wave >> 1) * 64;   // 4x2 wave grid: 64x64 out per wave
  int wc = (wave & 1) * 64;

  const unsigned short* gA = ghat + (size_t)(b * NN + row0) * KK;
  const unsigned short* gB = ghat + (size_t)(b * NN + col0) * KK;

  f32x4 acc[4][4];
#pragma unroll
  for (int i = 0; i < 4; ++i)
#pragma unroll
    for (int j = 0; j < 4; ++j)
      acc[i][j] = f32x4{0.f, 0.f, 0.f, 0.f};

  int rsel = lane & 15;        // fragment row selector
  int khalf = lane >> 4;       // k-chunk selector (0..3)
  int r8 = tid >> 3;           // staging row within 64-row group (0..63)
  int s8 = tid & 7;            // staging 16B slot (0..7)

  // 6 global_load_lds per thread per tile (4 A + 2 B) -> vmcnt math.
  auto STAGE = [&](int t, int bi) {
    int k0 = t * BKK;
#pragma unroll
    for (int i = 0; i < 4; ++i) {
      int rr = i * 64 + r8;
      int sg = s8 ^ (rr & 7);  // pre-swizzled global slot (both-sides XOR)
      gload16(gA + (size_t)rr * KK + k0 + sg * 8, &sm.s.A[bi][rr * BKK + s8 * 8]);
    }
#pragma unroll
    for (int i = 0; i < 2; ++i) {
      int rr = i * 64 + r8;
      int sg = s8 ^ (rr & 7);
      gload16(gB + (size_t)rr * KK + k0 + sg * 8, &sm.s.Bt[bi][rr * BKK + s8 * 8]);
    }
  };

  STAGE(0, 0);                 // prologue: tile 0 in flight (6 outstanding)

  for (int t = 0; t < NT; ++t) {
    int cb = t & 1;
    if (t + 1 < NT) {
      STAGE(t + 1, cb ^ 1);    // 12 outstanding; target buf finished compute
                               // at step t-1 and all waves passed that step's
                               // closing barrier.
      asm volatile("s_waitcnt vmcnt(6)" ::: "memory");   // tile t landed
    } else {
      asm volatile("s_waitcnt vmcnt(0)" ::: "memory");   // last tile: drain
    }
    __builtin_amdgcn_sched_barrier(0);
    __builtin_amdgcn_s_barrier();      // raw: all waves' tile-t data visible
    __builtin_amdgcn_sched_barrier(0);

    __builtin_amdgcn_s_setprio(1);
#pragma unroll
    for (int kk = 0; kk < 2; ++kk) {
      bf16x8 af[4], bfb[4];
#pragma unroll
      for (int i = 0; i < 4; ++i) {
        int rr = wr + i * 16 + rsel;
        int slot = (kk * 4 + khalf) ^ (rr & 7);
        af[i] = *(const bf16x8*)&sm.s.A[cb][rr * BKK + slot * 8];
      }
#pragma unroll
      for (int j = 0; j < 4; ++j) {
        int rr = wc + j * 16 + rsel;
        int slot = (kk * 4 + khalf) ^ (rr & 7);
        bfb[j] = *(const bf16x8*)&sm.s.Bt[cb][rr * BKK + slot * 8];
      }
#pragma unroll
      for (int i = 0; i < 4; ++i)
#pragma unroll
        for (int j = 0; j < 4; ++j)
          acc[i][j] = __builtin_amdgcn_mfma_f32_16x16x32_bf16(af[i], bfb[j], acc[i][j], 0, 0, 0);
    }
    __builtin_amdgcn_s_setprio(0);
    __builtin_amdgcn_s_barrier();      // compute-t done before buf reuse
  }
  __syncthreads();   // full drain once, before LDS union reuse

  // Gather u/v (flat layout) into LDS: R[rl][0..7]=u_row, [8..15]=v_row;
  // Cc[cl][0..7]=u_col, [8..15]=v_col.
  {
    int rl = tid >> 1;                 // 0..255
    int half = tid & 1;                // 0 = u, 1 = v
    const float* src = half ? vFlat : uFlat;
#pragma unroll
    for (int c = 0; c < 8; ++c)
      sm.e.R[rl][half * 8 + c] = src[(size_t)(b * NC + c) * NN + row0 + rl];
    if (rl < 128) {
#pragma unroll
      for (int c = 0; c < 8; ++c)
        sm.e.Cc[rl][half * 8 + c] = src[(size_t)(b * NC + c) * NN + col0 + rl];
    }
  }
  __syncthreads();

  int lr = (lane >> 4) * 4;
  int lc = lane & 15;
#pragma unroll
  for (int j = 0; j < 4; ++j) {
    int cl = wc + j * 16 + lc;
    f32x4 uc0 = *(const f32x4*)&sm.e.Cc[cl][0];
    f32x4 uc1 = *(const f32x4*)&sm.e.Cc[cl][4];
    f32x4 vc0 = *(const f32x4*)&sm.e.Cc[cl][8];
    f32x4 vc1 = *(const f32x4*)&sm.e.Cc[cl][12];
#pragma unroll
    for (int i = 0; i < 4; ++i) {
#pragma unroll
      for (int q = 0; q < 4; ++q) {
        int rl = wr + i * 16 + lr + q;
        f32x4 r0 = *(const f32x4*)&sm.e.R[rl][0];
        f32x4 r1 = *(const f32x4*)&sm.e.R[rl][4];
        f32x4 r2 = *(const f32x4*)&sm.e.R[rl][8];
        f32x4 r3 = *(const f32x4*)&sm.e.R[rl][12];
        float fr = r0[0]*vc0[0]+r0[1]*vc0[1]+r0[2]*vc0[2]+r0[3]*vc0[3]
                 + r1[0]*vc1[0]+r1[1]*vc1[1]+r1[2]*vc1[2]+r1[3]*vc1[3]
                 + r2[0]*uc0[0]+r2[1]*uc0[1]+r2[2]*uc0[2]+r2[3]*uc0[3]
                 + r3[0]*uc1[0]+r3[1]*uc1[1]+r3[2]*uc1[2]+r3[3]*uc1[3];
        float val = 0.125f * fr - 0.25f * acc[i][j][q];
        out[((size_t)(b * NN + row0 + rl)) * NN + (size_t)(col0 + cl)] = val;
      }
    }
  }
}

extern "C" void kernel_launch(void* const* d_in, const int* in_sizes, int n_in,
                              void* d_out, int out_size, void* d_ws, size_t ws_size,
                              hipStream_t stream) {
  const float* g = (const float*)d_in[0];
  // d_in[1] = patchPerRow (unused by the reference computation)
  unsigned short* ghat = (unsigned short*)d_ws;                          // 32 MiB bf16
  float* uFlat = (float*)((char*)d_ws + (size_t)NB * NN * KK * 2);       // 256 KiB
  float* vFlat = uFlat + (size_t)NB * NC * NN;                           // 256 KiB
  float* outp = (float*)d_out;

  prep_kernel<<<NB * NC * NN / 16, 256, 0, stream>>>(g, ghat, uFlat, vFlat);
  gram_gemm_kernel<<<256, 512, 0, stream>>>(ghat, uFlat, vFlat, outp);
}

// Round 8
// 199.789 us; speedup vs baseline: 1.4454x; 1.0011x over previous
//
#include <hip/hip_runtime.h>
#include <stdint.h>

#define NB 8
#define NC 8
#define NN 1024
#define ND 256
#define KK 2048      // NC * ND
#define NKB 256      // KK / 8  (16-byte k-chunks)

typedef float f32x4 __attribute__((ext_vector_type(4)));
typedef short bf16x8 __attribute__((ext_vector_type(8)));

__device__ __forceinline__ unsigned short f2bf(float x) {
  union { float f; uint32_t u; } a; a.f = x;
  uint32_t u = a.u;
  return (unsigned short)((u + 0x7FFFu + ((u >> 16) & 1u)) >> 16);  // RTNE
}

// Pass 1: per (b,c,n) row of 256 f32: sq=sum g^2, rnorm=rsqrt(sum g^4).
// Writes ghat_t in K-MAJOR fragment layout: [b][kb][n][8] bf16 (kb=k/8), so
// the GEMM can load MFMA fragments directly from global with 256B-contiguous
// segments (no LDS staging, no barriers in the K-loop).
// Store coalescing: per instr (fixed q), 4 consecutive rows x 2 subs fill
// full 64B lines at [kb][n..n+3][*]; 8 lines per instruction.
__global__ __launch_bounds__(256) void prep_kernel(
    const float* __restrict__ g, unsigned short* __restrict__ ghat_t,
    float* __restrict__ uFlat, float* __restrict__ vFlat) {
  int tid = threadIdx.x;
  int wave = tid >> 6, lane = tid & 63;
  int sub = lane & 15, grp = lane >> 4;
  int rowid = (blockIdx.x * 4 + wave) * 4 + grp;      // 16 rows per block, 4 consecutive per wave
  const float* row = g + (size_t)rowid * ND;
  f32x4 v[4];
  float s2 = 0.f, s4 = 0.f;
#pragma unroll
  for (int q = 0; q < 4; ++q) {
    v[q] = *(const f32x4*)(row + q * 64 + sub * 4);
#pragma unroll
    for (int e = 0; e < 4; ++e) { float x2 = v[q][e] * v[q][e]; s2 += x2; s4 += x2 * x2; }
  }
#pragma unroll
  for (int off = 8; off; off >>= 1) {                 // reduce within 16-lane group
    s2 += __shfl_xor(s2, off);
    s4 += __shfl_xor(s4, off);
  }
  float rn = rsqrtf(s4);
  int n = rowid & (NN - 1);
  int bc = rowid >> 10;
  int c = bc & (NC - 1);
  int b = bc >> 3;
#pragma unroll
  for (int q = 0; q < 4; ++q) {
    ushort4 o;
    o.x = f2bf(v[q][0] * rn); o.y = f2bf(v[q][1] * rn);
    o.z = f2bf(v[q][2] * rn); o.w = f2bf(v[q][3] * rn);
    // global k for this chunk = c*256 + q*64 + sub*4 ; kb = k/8 ; off = k%8
    int kb = c * 32 + q * 8 + (sub >> 1);
    unsigned short* dst =
        ghat_t + (((size_t)(b * NKB + kb)) * NN + n) * 8 + (sub & 1) * 4;
    *(ushort4*)dst = o;
  }
  if (sub == 0) { uFlat[rowid] = s2 * rn; vFlat[rowid] = rn; }
}

// Pass 2: per b, out = 0.125*(u_n.v_m + v_n.u_m) - 0.25 * <ghat_n, ghat_m>
// Direct global->VGPR MFMA fragments from the K-major layout. No LDS, no
// barriers in the K-loop: per K-step(32) per wave = 8 x b128 loads (each 4
// x 256B contiguous segments) + 16 MFMA. Compiler software-pipelines across
// steps; TLP unconstrained (12 KiB LDS used only by the epilogue).
__global__ __launch_bounds__(256) void gram_gemm_kernel(
    const unsigned short* __restrict__ ghat_t,
    const float* __restrict__ uFlat, const float* __restrict__ vFlat,
    float* __restrict__ out) {
  __shared__ struct { float R[128][16]; float Cc[128][16]; } sm;  // epilogue only

  // XCD swizzle: 512 blocks, 8 XCDs -> 64 consecutive logical tiles
  // (= one batch b, one 4MiB ghat_t panel) per XCD L2.
  int bid = blockIdx.x;
  int logical = (bid & 7) * 64 + (bid >> 3);
  int b = logical >> 6;
  int t6 = logical & 63;
  int row0 = (t6 >> 3) * 128;
  int col0 = (t6 & 7) * 128;
  int tid = threadIdx.x;
  int lane = tid & 63;
  int wave = tid >> 6;
  int wr = (wave >> 1) * 64;   // 2x2 wave grid: 64x64 out per wave
  int wc = (wave & 1) * 64;

  int rsel = lane & 15;        // fragment row selector
  int kq = lane >> 4;          // k-chunk selector (0..3)

  // Per-lane base pointers into [b][kb][n][8]; n-stride = 8 elems (16B).
  const unsigned short* pA =
      ghat_t + (((size_t)(b * NKB) + kq) * NN + row0 + wr + rsel) * 8;
  const unsigned short* pB =
      ghat_t + (((size_t)(b * NKB) + kq) * NN + col0 + wc + rsel) * 8;

  f32x4 acc[4][4];
#pragma unroll
  for (int i = 0; i < 4; ++i)
#pragma unroll
    for (int j = 0; j < 4; ++j)
      acc[i][j] = f32x4{0.f, 0.f, 0.f, 0.f};

  // K-step = 32 elems = 4 kb; per-step pointer advance = 4*NN*8 elems.
#pragma unroll 2
  for (int t = 0; t < KK / 32; ++t) {
    size_t koff = (size_t)t * 4 * NN * 8;
    bf16x8 af[4], bfb[4];
#pragma unroll
    for (int i = 0; i < 4; ++i)
      af[i] = *(const bf16x8*)(pA + koff + i * 16 * 8);
#pragma unroll
    for (int j = 0; j < 4; ++j)
      bfb[j] = *(const bf16x8*)(pB + koff + j * 16 * 8);
#pragma unroll
    for (int i = 0; i < 4; ++i)
#pragma unroll
      for (int j = 0; j < 4; ++j)
        acc[i][j] = __builtin_amdgcn_mfma_f32_16x16x32_bf16(af[i], bfb[j], acc[i][j], 0, 0, 0);
  }

  // Gather u/v (flat layout) into LDS: R[rl][0..7]=u_row, [8..15]=v_row;
  // Cc[cl][0..7]=u_col, [8..15]=v_col.
  {
    int rl = tid >> 1;                 // 0..127
    int half = tid & 1;                // 0 = u, 1 = v
    const float* src = half ? vFlat : uFlat;
#pragma unroll
    for (int c = 0; c < 8; ++c) {
      sm.R[rl][half * 8 + c] = src[(size_t)(b * NC + c) * NN + row0 + rl];
      sm.Cc[rl][half * 8 + c] = src[(size_t)(b * NC + c) * NN + col0 + rl];
    }
  }
  __syncthreads();

  int lr = (lane >> 4) * 4;
  int lc = lane & 15;
#pragma unroll
  for (int j = 0; j < 4; ++j) {
    int cl = wc + j * 16 + lc;
    f32x4 uc0 = *(const f32x4*)&sm.Cc[cl][0];
    f32x4 uc1 = *(const f32x4*)&sm.Cc[cl][4];
    f32x4 vc0 = *(const f32x4*)&sm.Cc[cl][8];
    f32x4 vc1 = *(const f32x4*)&sm.Cc[cl][12];
#pragma unroll
    for (int i = 0; i < 4; ++i) {
#pragma unroll
      for (int q = 0; q < 4; ++q) {
        int rl = wr + i * 16 + lr + q;
        f32x4 r0 = *(const f32x4*)&sm.R[rl][0];
        f32x4 r1 = *(const f32x4*)&sm.R[rl][4];
        f32x4 r2 = *(const f32x4*)&sm.R[rl][8];
        f32x4 r3 = *(const f32x4*)&sm.R[rl][12];
        float fr = r0[0]*vc0[0]+r0[1]*vc0[1]+r0[2]*vc0[2]+r0[3]*vc0[3]
                 + r1[0]*vc1[0]+r1[1]*vc1[1]+r1[2]*vc1[2]+r1[3]*vc1[3]
                 + r2[0]*uc0[0]+r2[1]*uc0[1]+r2[2]*uc0[2]+r2[3]*uc0[3]
                 + r3[0]*uc1[0]+r3[1]*uc1[1]+r3[2]*uc1[2]+r3[3]*uc1[3];
        float val = 0.125f * fr - 0.25f * acc[i][j][q];
        out[((size_t)(b * NN + row0 + rl)) * NN + (size_t)(col0 + cl)] = val;
      }
    }
  }
}

extern "C" void kernel_launch(void* const* d_in, const int* in_sizes, int n_in,
                              void* d_out, int out_size, void* d_ws, size_t ws_size,
                              hipStream_t stream) {
  const float* g = (const float*)d_in[0];
  // d_in[1] = patchPerRow (unused by the reference computation)
  unsigned short* ghat_t = (unsigned short*)d_ws;                        // 32 MiB bf16, [b][kb][n][8]
  float* uFlat = (float*)((char*)d_ws + (size_t)NB * NN * KK * 2);       // 256 KiB
  float* vFlat = uFlat + (size_t)NB * NC * NN;                           // 256 KiB
  float* outp = (float*)d_out;

  prep_kernel<<<NB * NC * NN / 16, 256, 0, stream>>>(g, ghat_t, uFlat, vFlat);
  gram_gemm_kernel<<<512, 256, 0, stream>>>(ghat_t, uFlat, vFlat, outp);
}